// Round 1
// baseline (996.374 us; speedup 1.0000x reference)
//
#include <hip/hip_runtime.h>
#include <math.h>

#define B_ 128
#define T_ 1024
#define H_ 256
#define Z_ 64
#define M_ (B_ * T_)   // 131072 rows

// ---------------------------------------------------------------------------
// Kernel 1: precompute the non-recurrent part of both matmuls.
//   pre_mu[m, n]  = sum_k H[m,k] * W_mu[n,k]  + b_mu[n]    (k over 0..255)
//   pre_std[m, n] = sum_k H[m,k] * W_std[n,k] + b_std[n]
// Tiled f32 GEMM: block = 256 threads (16x16), tile 64(M) x 64(N), K-step 16.
// Each thread computes a 4x4 micro-tile for BOTH mu and std (A-tile reuse).
// ---------------------------------------------------------------------------
__global__ __launch_bounds__(256) void precompute_kernel(
    const float* __restrict__ Hm,    // [M_, 256]
    const float* __restrict__ Wmu,   // [64, 320]
    const float* __restrict__ Wstd,  // [64, 320]
    const float* __restrict__ bmu,   // [64]
    const float* __restrict__ bstd,  // [64]
    float* __restrict__ pre_mu,      // [M_, 64]
    float* __restrict__ pre_std)     // [M_, 64]
{
    const int tid = threadIdx.x;
    const int ty = tid >> 4;          // 0..15 -> 4 M-rows each
    const int tx = tid & 15;          // 0..15 -> 4 N-cols each
    const int m0 = blockIdx.x * 64;

    __shared__ float Ash[64][17];     // +1 pad: kills power-of-2 bank conflicts
    __shared__ float Wm[64][17];
    __shared__ float Ws[64][17];

    float accm[4][4] = {};
    float accs[4][4] = {};

    const int lrow = tid >> 2;        // 0..63
    const int lk   = (tid & 3) * 4;   // 0,4,8,12

    for (int k0 = 0; k0 < 256; k0 += 16) {
        float4 av  = *reinterpret_cast<const float4*>(&Hm[(size_t)(m0 + lrow) * H_ + k0 + lk]);
        float4 wmv = *reinterpret_cast<const float4*>(&Wmu[(size_t)lrow * 320 + k0 + lk]);
        float4 wsv = *reinterpret_cast<const float4*>(&Wstd[(size_t)lrow * 320 + k0 + lk]);
        __syncthreads();   // all threads done reading previous tiles
        Ash[lrow][lk + 0] = av.x;  Ash[lrow][lk + 1] = av.y;
        Ash[lrow][lk + 2] = av.z;  Ash[lrow][lk + 3] = av.w;
        Wm[lrow][lk + 0] = wmv.x;  Wm[lrow][lk + 1] = wmv.y;
        Wm[lrow][lk + 2] = wmv.z;  Wm[lrow][lk + 3] = wmv.w;
        Ws[lrow][lk + 0] = wsv.x;  Ws[lrow][lk + 1] = wsv.y;
        Ws[lrow][lk + 2] = wsv.z;  Ws[lrow][lk + 3] = wsv.w;
        __syncthreads();

        #pragma unroll
        for (int kk = 0; kk < 16; ++kk) {
            float a4[4], wm4[4], ws4[4];
            #pragma unroll
            for (int i = 0; i < 4; ++i) a4[i] = Ash[ty * 4 + i][kk];
            #pragma unroll
            for (int jj = 0; jj < 4; ++jj) wm4[jj] = Wm[tx * 4 + jj][kk];
            #pragma unroll
            for (int jj = 0; jj < 4; ++jj) ws4[jj] = Ws[tx * 4 + jj][kk];
            #pragma unroll
            for (int i = 0; i < 4; ++i)
                #pragma unroll
                for (int jj = 0; jj < 4; ++jj) {
                    accm[i][jj] += a4[i] * wm4[jj];
                    accs[i][jj] += a4[i] * ws4[jj];
                }
        }
    }

    // epilogue: add bias, vectorized store
    float4 bm = *reinterpret_cast<const float4*>(&bmu[tx * 4]);
    float4 bs = *reinterpret_cast<const float4*>(&bstd[tx * 4]);
    #pragma unroll
    for (int i = 0; i < 4; ++i) {
        const size_t m = (size_t)(m0 + ty * 4 + i);
        float4 om, os;
        om.x = accm[i][0] + bm.x;  om.y = accm[i][1] + bm.y;
        om.z = accm[i][2] + bm.z;  om.w = accm[i][3] + bm.w;
        os.x = accs[i][0] + bs.x;  os.y = accs[i][1] + bs.y;
        os.z = accs[i][2] + bs.z;  os.w = accs[i][3] + bs.w;
        *reinterpret_cast<float4*>(&pre_mu[m * Z_ + tx * 4])  = om;
        *reinterpret_cast<float4*>(&pre_std[m * Z_ + tx * 4]) = os;
    }
}

// ---------------------------------------------------------------------------
// Kernel 2: the recurrence. One wave (64 lanes) per batch row; lane j owns
// output element j. Recurrent weights A = W[:, 256:320] live in registers
// (128 VGPRs). z_{t-1} is broadcast from LDS via ds_read_b128 (same-address
// broadcast across lanes = conflict-free). Double-buffered z removes the
// write-after-read hazard so one __syncthreads per step suffices (single
// wave -> barrier is nearly free, supplies the lgkmcnt wait we need anyway).
// pre/eps loads for step t+1 issue at the top of step t (latency hidden).
// ---------------------------------------------------------------------------
__global__ __launch_bounds__(64) void recurrent_kernel(
    const float* __restrict__ pre_mu,   // [M_, 64]
    const float* __restrict__ pre_std,  // [M_, 64]
    const float* __restrict__ eps,      // [B_, T_, 64]
    const float* __restrict__ Wmu,      // [64, 320]
    const float* __restrict__ Wstd,     // [64, 320]
    float* __restrict__ out)            // z | mu | std, each [B_, T_, 64]
{
    const int b = blockIdx.x;
    const int j = threadIdx.x;

    // recurrent weight rows in registers (fully unrolled -> static indices)
    float amu[64], astd[64];
    #pragma unroll
    for (int k = 0; k < 64; ++k) {
        amu[k]  = Wmu[(size_t)j * 320 + 256 + k];
        astd[k] = Wstd[(size_t)j * 320 + 256 + k];
    }

    __shared__ float zs[2][64];
    zs[0][j] = 0.0f;
    __syncthreads();

    const size_t base = (size_t)b * T_ * Z_;
    float* __restrict__ zo   = out;
    float* __restrict__ muo  = out + (size_t)M_ * Z_;
    float* __restrict__ stdo = out + (size_t)2 * M_ * Z_;

    // prefetch t = 0
    float pm = pre_mu[base + j];
    float ps = pre_std[base + j];
    float ev = eps[base + j];

    for (int t = 0; t < T_; ++t) {
        // prefetch t+1 (hidden under this step's matvec)
        float pm_n = 0.f, ps_n = 0.f, ev_n = 0.f;
        if (t + 1 < T_) {
            const size_t idx = base + (size_t)(t + 1) * Z_ + j;
            pm_n = pre_mu[idx];
            ps_n = pre_std[idx];
            ev_n = eps[idx];
        }

        const float4* __restrict__ z4 =
            reinterpret_cast<const float4*>(zs[t & 1]);
        float am0 = pm, am1 = 0.f, am2 = 0.f, am3 = 0.f;
        float as0 = ps, as1 = 0.f, as2 = 0.f, as3 = 0.f;
        #pragma unroll
        for (int k = 0; k < 16; ++k) {
            const float4 q = z4[k];   // broadcast read, conflict-free
            am0 += q.x * amu[4 * k + 0];  as0 += q.x * astd[4 * k + 0];
            am1 += q.y * amu[4 * k + 1];  as1 += q.y * astd[4 * k + 1];
            am2 += q.z * amu[4 * k + 2];  as2 += q.z * astd[4 * k + 2];
            am3 += q.w * amu[4 * k + 3];  as3 += q.w * astd[4 * k + 3];
        }
        const float mu = (am0 + am1) + (am2 + am3);
        const float sx = (as0 + as1) + (as2 + as3);
        const float sp = (sx > 20.0f) ? sx : log1pf(__expf(sx));
        const float sd = sp + 1e-4f;
        const float z  = mu + ev * sd;

        const size_t o = base + (size_t)t * Z_ + j;
        zo[o]   = z;
        muo[o]  = mu;
        stdo[o] = sd;

        zs[(t + 1) & 1][j] = z;
        __syncthreads();   // publish z_t for next step's broadcast reads

        pm = pm_n; ps = ps_n; ev = ev_n;
    }
}

extern "C" void kernel_launch(void* const* d_in, const int* in_sizes, int n_in,
                              void* d_out, int out_size, void* d_ws, size_t ws_size,
                              hipStream_t stream) {
    const float* input_q = (const float*)d_in[0];  // [B, T, H]
    const float* eps     = (const float*)d_in[1];  // [B, T, Z]
    const float* W_mu    = (const float*)d_in[2];  // [Z, H+Z]
    const float* b_mu    = (const float*)d_in[3];  // [Z]
    const float* W_std   = (const float*)d_in[4];  // [Z, H+Z]
    const float* b_std   = (const float*)d_in[5];  // [Z]
    float* out = (float*)d_out;

    float* pre_mu  = (float*)d_ws;                      // [M_, 64]
    float* pre_std = pre_mu + (size_t)M_ * Z_;          // [M_, 64]

    precompute_kernel<<<M_ / 64, 256, 0, stream>>>(
        input_q, W_mu, W_std, b_mu, b_std, pre_mu, pre_std);

    recurrent_kernel<<<B_, 64, 0, stream>>>(
        pre_mu, pre_std, eps, W_mu, W_std, out);
}

// Round 2
// 908.422 us; speedup vs baseline: 1.0968x; 1.0968x over previous
//
#include <hip/hip_runtime.h>
#include <math.h>

#define B_ 128
#define T_ 1024
#define H_ 256
#define Z_ 64
#define M_ (B_ * T_)   // 131072 rows

// ---------------------------------------------------------------------------
// Kernel 1: precompute the non-recurrent part of both matmuls.
//   pre_mu[m, n]  = sum_k H[m,k] * W_mu[n,k]  + b_mu[n]    (k over 0..255)
//   pre_std[m, n] = sum_k H[m,k] * W_std[n,k] + b_std[n]
// Tiled f32 GEMM: block = 256 threads (16x16), tile 64(M) x 64(N), K-step 16.
// ---------------------------------------------------------------------------
__global__ __launch_bounds__(256) void precompute_kernel(
    const float* __restrict__ Hm,    // [M_, 256]
    const float* __restrict__ Wmu,   // [64, 320]
    const float* __restrict__ Wstd,  // [64, 320]
    const float* __restrict__ bmu,   // [64]
    const float* __restrict__ bstd,  // [64]
    float* __restrict__ pre_mu,      // [M_, 64]
    float* __restrict__ pre_std)     // [M_, 64]
{
    const int tid = threadIdx.x;
    const int ty = tid >> 4;          // 0..15 -> 4 M-rows each
    const int tx = tid & 15;          // 0..15 -> 4 N-cols each
    const int m0 = blockIdx.x * 64;

    __shared__ float Ash[64][17];     // +1 pad: kills power-of-2 bank conflicts
    __shared__ float Wm[64][17];
    __shared__ float Ws[64][17];

    float accm[4][4] = {};
    float accs[4][4] = {};

    const int lrow = tid >> 2;        // 0..63
    const int lk   = (tid & 3) * 4;   // 0,4,8,12

    for (int k0 = 0; k0 < 256; k0 += 16) {
        float4 av  = *reinterpret_cast<const float4*>(&Hm[(size_t)(m0 + lrow) * H_ + k0 + lk]);
        float4 wmv = *reinterpret_cast<const float4*>(&Wmu[(size_t)lrow * 320 + k0 + lk]);
        float4 wsv = *reinterpret_cast<const float4*>(&Wstd[(size_t)lrow * 320 + k0 + lk]);
        __syncthreads();   // all threads done reading previous tiles
        Ash[lrow][lk + 0] = av.x;  Ash[lrow][lk + 1] = av.y;
        Ash[lrow][lk + 2] = av.z;  Ash[lrow][lk + 3] = av.w;
        Wm[lrow][lk + 0] = wmv.x;  Wm[lrow][lk + 1] = wmv.y;
        Wm[lrow][lk + 2] = wmv.z;  Wm[lrow][lk + 3] = wmv.w;
        Ws[lrow][lk + 0] = wsv.x;  Ws[lrow][lk + 1] = wsv.y;
        Ws[lrow][lk + 2] = wsv.z;  Ws[lrow][lk + 3] = wsv.w;
        __syncthreads();

        #pragma unroll
        for (int kk = 0; kk < 16; ++kk) {
            float a4[4], wm4[4], ws4[4];
            #pragma unroll
            for (int i = 0; i < 4; ++i) a4[i] = Ash[ty * 4 + i][kk];
            #pragma unroll
            for (int jj = 0; jj < 4; ++jj) wm4[jj] = Wm[tx * 4 + jj][kk];
            #pragma unroll
            for (int jj = 0; jj < 4; ++jj) ws4[jj] = Ws[tx * 4 + jj][kk];
            #pragma unroll
            for (int i = 0; i < 4; ++i)
                #pragma unroll
                for (int jj = 0; jj < 4; ++jj) {
                    accm[i][jj] += a4[i] * wm4[jj];
                    accs[i][jj] += a4[i] * ws4[jj];
                }
        }
    }

    float4 bm = *reinterpret_cast<const float4*>(&bmu[tx * 4]);
    float4 bs = *reinterpret_cast<const float4*>(&bstd[tx * 4]);
    #pragma unroll
    for (int i = 0; i < 4; ++i) {
        const size_t m = (size_t)(m0 + ty * 4 + i);
        float4 om, os;
        om.x = accm[i][0] + bm.x;  om.y = accm[i][1] + bm.y;
        om.z = accm[i][2] + bm.z;  om.w = accm[i][3] + bm.w;
        os.x = accs[i][0] + bs.x;  os.y = accs[i][1] + bs.y;
        os.z = accs[i][2] + bs.z;  os.w = accs[i][3] + bs.w;
        *reinterpret_cast<float4*>(&pre_mu[m * Z_ + tx * 4])  = om;
        *reinterpret_cast<float4*>(&pre_std[m * Z_ + tx * 4]) = os;
    }
}

// ---------------------------------------------------------------------------
// Kernel 2: the recurrence. One wave per batch row; lane j owns output
// element j. z_{t-1} never leaves registers: each step broadcasts the 64
// lane-private z values with v_readlane_b32 -> SGPR, which feeds v_fmac_f32
// directly (one SGPR operand per VALU instr is legal). NO LDS, NO barrier:
// this removes the s_waitcnt vmcnt(0) barrier-drain that put store/load
// latency on the loop-carried critical path (R1: 1980 cyc/step observed vs
// ~420 issue cycles of real work). Softplus via hardware v_exp/v_log.
// ---------------------------------------------------------------------------
__global__ __launch_bounds__(64) void recurrent_kernel(
    const float* __restrict__ pre_mu,   // [M_, 64]
    const float* __restrict__ pre_std,  // [M_, 64]
    const float* __restrict__ eps,      // [B_, T_, 64]
    const float* __restrict__ Wmu,      // [64, 320]
    const float* __restrict__ Wstd,     // [64, 320]
    float* __restrict__ out)            // z | mu | std, each [B_, T_, 64]
{
    const int b = blockIdx.x;
    const int j = threadIdx.x;

    // recurrent weight rows in registers (fully unrolled -> static indices)
    float amu[64], astd[64];
    #pragma unroll
    for (int k = 0; k < 64; ++k) {
        amu[k]  = Wmu[(size_t)j * 320 + 256 + k];
        astd[k] = Wstd[(size_t)j * 320 + 256 + k];
    }

    const size_t base = (size_t)b * T_ * Z_;
    float* __restrict__ zo   = out;
    float* __restrict__ muo  = out + (size_t)M_ * Z_;
    float* __restrict__ stdo = out + (size_t)2 * M_ * Z_;

    // prefetch t = 0
    float pm = pre_mu[base + j];
    float ps = pre_std[base + j];
    float ev = eps[base + j];

    float z = 0.0f;   // z_{t-1}, lane j holds element j

    for (int t = 0; t < T_; ++t) {
        // prefetch t+1 (overlaps with this step's matvec; no barrier drain)
        float pm_n = 0.f, ps_n = 0.f, ev_n = 0.f;
        if (t + 1 < T_) {
            const size_t idx = base + (size_t)(t + 1) * Z_ + j;
            pm_n = pre_mu[idx];
            ps_n = pre_std[idx];
            ev_n = eps[idx];
        }

        // wave-broadcast matvec: 4 accumulators per output to break dep chains
        const unsigned zb = __float_as_uint(z);
        float am0 = pm, am1 = 0.f, am2 = 0.f, am3 = 0.f;
        float as0 = ps, as1 = 0.f, as2 = 0.f, as3 = 0.f;
        #pragma unroll
        for (int k = 0; k < 16; ++k) {
            const float z0 = __uint_as_float(__builtin_amdgcn_readlane(zb, 4 * k + 0));
            const float z1 = __uint_as_float(__builtin_amdgcn_readlane(zb, 4 * k + 1));
            const float z2 = __uint_as_float(__builtin_amdgcn_readlane(zb, 4 * k + 2));
            const float z3 = __uint_as_float(__builtin_amdgcn_readlane(zb, 4 * k + 3));
            am0 += z0 * amu[4 * k + 0];  as0 += z0 * astd[4 * k + 0];
            am1 += z1 * amu[4 * k + 1];  as1 += z1 * astd[4 * k + 1];
            am2 += z2 * amu[4 * k + 2];  as2 += z2 * astd[4 * k + 2];
            am3 += z3 * amu[4 * k + 3];  as3 += z3 * astd[4 * k + 3];
        }
        const float mu = (am0 + am1) + (am2 + am3);
        const float sx = (as0 + as1) + (as2 + as3);
        // softplus via hw transcendentals (abs err < 1e-7 in guarded range)
        const float sp = (sx > 20.0f) ? sx : __logf(1.0f + __expf(sx));
        const float sd = sp + 1e-4f;
        z = mu + ev * sd;

        const size_t o = base + (size_t)t * Z_ + j;
        zo[o]   = z;
        muo[o]  = mu;
        stdo[o] = sd;

        pm = pm_n; ps = ps_n; ev = ev_n;
    }
}

extern "C" void kernel_launch(void* const* d_in, const int* in_sizes, int n_in,
                              void* d_out, int out_size, void* d_ws, size_t ws_size,
                              hipStream_t stream) {
    const float* input_q = (const float*)d_in[0];  // [B, T, H]
    const float* eps     = (const float*)d_in[1];  // [B, T, Z]
    const float* W_mu    = (const float*)d_in[2];  // [Z, H+Z]
    const float* b_mu    = (const float*)d_in[3];  // [Z]
    const float* W_std   = (const float*)d_in[4];  // [Z, H+Z]
    const float* b_std   = (const float*)d_in[5];  // [Z]
    float* out = (float*)d_out;

    float* pre_mu  = (float*)d_ws;                      // [M_, 64]
    float* pre_std = pre_mu + (size_t)M_ * Z_;          // [M_, 64]

    precompute_kernel<<<M_ / 64, 256, 0, stream>>>(
        input_q, W_mu, W_std, b_mu, b_std, pre_mu, pre_std);

    recurrent_kernel<<<B_, 64, 0, stream>>>(
        pre_mu, pre_std, eps, W_mu, W_std, out);
}